// Round 9
// baseline (678.391 us; speedup 1.0000x reference)
//
#include <hip/hip_runtime.h>
#include <hip/hip_bf16.h>

// ---------------------------------------------------------------------------
// GIN model, proj-first formulation, fused per-layer kernel:
//   proj:  y0 = x @ w1_0                  (bf16 y, STRIP-MAJOR: 4 strips x 16f)
//   fused: t = relu(y_self + sum_nbr y + b1)   (LDS, fp32; gather per strip,
//          chunk-major so each 3.2MB strip is L2-resident per XCD)
//          u = relu(t @ w2 + b2)
//          y' = u @ w1_next (bf16 strips)  |  h = u (fp32, last layer)
// CSR built per call via bucketed counting sort. Pool: 2-stage + head MLP.
// ---------------------------------------------------------------------------

__device__ inline unsigned short f2bf(float f) {
    union { __hip_bfloat16 b; unsigned short u; } cv;
    cv.b = __float2bfloat16(f);
    return cv.u;
}
__device__ inline float bflo(unsigned int v) {
    union { unsigned int u; float f; } c; c.u = v << 16; return c.f;
}
__device__ inline float bfhi(unsigned int v) {
    union { unsigned int u; float f; } c; c.u = v & 0xffff0000u; return c.f;
}

__global__ __launch_bounds__(1024) void zero1024_kernel(int* __restrict__ p) {
    p[threadIdx.x] = 0;
}

__global__ __launch_bounds__(256) void count_buckets_kernel(
    const int* __restrict__ ei, int* __restrict__ gcount, int E_) {
    __shared__ int hist[1024];
    const int tid = threadIdx.x;
    for (int i = tid; i < 1024; i += 256) hist[i] = 0;
    __syncthreads();
    const int base = blockIdx.x * 2048;
#pragma unroll
    for (int i = 0; i < 8; i++) {
        int e = base + i * 256 + tid;
        if (e < E_) atomicAdd(&hist[ei[E_ + e] >> 9], 1);
    }
    __syncthreads();
    for (int i = tid; i < 1024; i += 256)
        if (hist[i]) atomicAdd(&gcount[i], hist[i]);
}

__global__ __launch_bounds__(1024) void scan_buckets_kernel(
    const int* __restrict__ gcount, int* __restrict__ bbase,
    int* __restrict__ gcursor, int* __restrict__ rowptr, int K, int E_, int n) {
    __shared__ int sd[1024];
    const int tid = threadIdx.x;
    int v = (tid < K) ? gcount[tid] : 0;
    sd[tid] = v;
    __syncthreads();
    for (int off = 1; off < 1024; off <<= 1) {
        int x = (tid >= off) ? sd[tid - off] : 0;
        __syncthreads();
        sd[tid] += x;
        __syncthreads();
    }
    if (tid < K) {
        int excl = sd[tid] - v;
        bbase[tid] = excl;
        gcursor[tid] = excl;
    }
    if (tid == 0) {
        bbase[K] = E_;
        rowptr[n] = E_;
    }
}

__global__ __launch_bounds__(256) void bucketize_kernel(
    const int* __restrict__ ei, int* __restrict__ gcursor,
    unsigned* __restrict__ bpack, int E_) {
    __shared__ int hist[1024];
    __shared__ int gbase[1024];
    const int tid = threadIdx.x;
    for (int i = tid; i < 1024; i += 256) hist[i] = 0;
    __syncthreads();
    const int base = blockIdx.x * 2048;
    int bkt[8], rnk[8];
    unsigned pk[8];
#pragma unroll
    for (int i = 0; i < 8; i++) {
        int e = base + i * 256 + tid;
        bkt[i] = -1;
        if (e < E_) {
            int s = ei[e];
            int d = ei[E_ + e];
            bkt[i] = d >> 9;
            pk[i] = (unsigned)s | ((unsigned)(d & 511) << 22);
            rnk[i] = atomicAdd(&hist[bkt[i]], 1);
        }
    }
    __syncthreads();
    for (int i = tid; i < 1024; i += 256)
        if (hist[i]) gbase[i] = atomicAdd(&gcursor[i], hist[i]);
    __syncthreads();
#pragma unroll
    for (int i = 0; i < 8; i++)
        if (bkt[i] >= 0) bpack[gbase[bkt[i]] + rnk[i]] = pk[i];
}

__global__ __launch_bounds__(256) void build_csr_kernel(
    const unsigned* __restrict__ bpack, const int* __restrict__ bbase,
    int* __restrict__ rowptr, int* __restrict__ col, int n) {
    __shared__ int cnt[512];
    __shared__ int sp[256];
    const int tid = threadIdx.x;
    const int b = blockIdx.x;
    const int nstart = b << 9;
    const int estart = bbase[b];
    const int eend = bbase[b + 1];
    cnt[tid] = 0;
    cnt[tid + 256] = 0;
    __syncthreads();
    for (int e = estart + tid; e < eend; e += 256)
        atomicAdd(&cnt[bpack[e] >> 22], 1);
    __syncthreads();
    const int v0 = cnt[tid * 2], v1 = cnt[tid * 2 + 1];
    const int s = v0 + v1;
    sp[tid] = s;
    __syncthreads();
    for (int off = 1; off < 256; off <<= 1) {
        int x = (tid >= off) ? sp[tid - off] : 0;
        __syncthreads();
        sp[tid] += x;
        __syncthreads();
    }
    const int excl = sp[tid] - s;
    cnt[tid * 2] = excl;
    cnt[tid * 2 + 1] = excl + v0;
    const int node0 = nstart + tid * 2;
    if (node0 < n) rowptr[node0] = estart + excl;
    if (node0 + 1 < n) rowptr[node0 + 1] = estart + excl + v0;
    __syncthreads();
    for (int e = estart + tid; e < eend; e += 256) {
        unsigned p = bpack[e];
        int pos = estart + atomicAdd(&cnt[p >> 22], 1);
        col[pos] = (int)(p & 0x3FFFFFu);
    }
}

// ---------------------------------------------------------------------------
// proj128: y(bf16, strip-major) = x[n,128] @ w[128,64]; x staged bf16x2 in LDS.
// Wave wv computes features wv*16..wv*16+16 == strip wv.
// ---------------------------------------------------------------------------
__global__ __launch_bounds__(256) void proj128_kernel(
    const float* __restrict__ x, unsigned short* __restrict__ y,
    const float* __restrict__ w, int n) {
    constexpr int STR = 66;              // u32 stride (2-way bank alias: free)
    __shared__ unsigned int xs[64 * STR];
    const int tid = threadIdx.x;
    const int tile = blockIdx.x;
    for (int idx = tid; idx < 64 * 64; idx += 256) {
        int r = idx >> 6;
        int c = idx & 63;
        int node = tile * 64 + r;
        float2 v = make_float2(0.f, 0.f);
        if (node < n) v = *reinterpret_cast<const float2*>(x + (size_t)node * 128 + c * 2);
        xs[r * STR + c] = (unsigned)f2bf(v.x) | ((unsigned)f2bf(v.y) << 16);
    }
    __syncthreads();
    const int lane = tid & 63;
    const int wv = __builtin_amdgcn_readfirstlane(tid >> 6);
    const int j0 = wv << 4;
    float a[16];
#pragma unroll
    for (int jj = 0; jj < 16; jj++) a[jj] = 0.f;
    for (int k = 0; k < 128; k += 8) {
        unsigned p0 = xs[lane * STR + k / 2 + 0];
        unsigned p1 = xs[lane * STR + k / 2 + 1];
        unsigned p2 = xs[lane * STR + k / 2 + 2];
        unsigned p3 = xs[lane * STR + k / 2 + 3];
        const float tv[8] = {bflo(p0), bfhi(p0), bflo(p1), bfhi(p1),
                             bflo(p2), bfhi(p2), bflo(p3), bfhi(p3)};
#pragma unroll
        for (int kk = 0; kk < 8; kk++)
#pragma unroll
            for (int jj = 0; jj < 16; jj++)
                a[jj] = fmaf(tv[kk], w[(k + kk) * 64 + j0 + jj], a[jj]);
    }
    const int node = tile * 64 + lane;
    if (node < n) {
        unsigned pk[8];
#pragma unroll
        for (int jj = 0; jj < 8; jj++)
            pk[jj] = (unsigned)f2bf(a[2 * jj]) | ((unsigned)f2bf(a[2 * jj + 1]) << 16);
        unsigned* yo = reinterpret_cast<unsigned*>(y) + (size_t)wv * n * 8 + (size_t)node * 8;
        uint4* o = reinterpret_cast<uint4*>(yo);
        o[0] = make_uint4(pk[0], pk[1], pk[2], pk[3]);
        o[1] = make_uint4(pk[4], pk[5], pk[6], pk[7]);
    }
}

// ---------------------------------------------------------------------------
// fused_layer: per 64-node tile
//   A: gather per strip c=0..3 (chunk-major; 3.2MB strip L2-resident):
//      lane = (slot e8 = lane>>3) x (feat-pair f8 = lane&7); 8 edges/round,
//      2 rounds in flight; combine via shfl_xor(8,16,32).
//   B: u = relu(t @ w2 + b2)
//   C/D (mid): y' = u @ w1n (bf16 strips)   |  (last): h = u (fp32)
// ---------------------------------------------------------------------------
template <bool LAST>
__global__ __launch_bounds__(256) void fused_layer_kernel(
    const unsigned short* __restrict__ yin,
    const int* __restrict__ rowptr, const int* __restrict__ col,
    const float* __restrict__ b1,
    const float* __restrict__ w2, const float* __restrict__ b2,
    const float* __restrict__ w1n,
    unsigned short* __restrict__ yout, float* __restrict__ hout, int n) {
    constexpr int STR = 66;
    __shared__ float tl[64 * STR];
    const int tid = threadIdx.x;
    const int tile = blockIdx.x;
    const int lane = tid & 63;
    const int wv = __builtin_amdgcn_readfirstlane(tid >> 6);
    const int e8 = lane >> 3;
    const int f8 = lane & 7;
    const unsigned int* y32 = reinterpret_cast<const unsigned int*>(yin);
    const size_t n8 = (size_t)n * 8;

    // ---- Phase A: strip-chunked gather ----
    for (int c = 0; c < 4; ++c) {
        const unsigned int* yb = y32 + (size_t)c * n8;
        const float2 bv = *reinterpret_cast<const float2*>(b1 + c * 16 + 2 * f8);
        for (int i = 0; i < 16; ++i) {
            const int node = tile * 64 + wv * 16 + i;
            if (node >= n) break;  // ascending; uniform per wave
            const int rs = rowptr[node];
            const int deg = rowptr[node + 1] - rs;
            // self strip (counted once, by slot-group 0)
            const unsigned sv = yb[(size_t)node * 8 + f8];
            const float m = (e8 == 0) ? 1.f : 0.f;
            float ax = m * bflo(sv);
            float ay = m * bfhi(sv);
            int base = 0;
            for (; base + 16 <= deg; base += 16) {   // 2 rounds in flight
                const int c0 = col[rs + base + e8];
                const int c1 = col[rs + base + 8 + e8];
                const unsigned v0 = yb[(size_t)c0 * 8 + f8];
                const unsigned v1 = yb[(size_t)c1 * 8 + f8];
                ax += bflo(v0); ay += bfhi(v0);
                ax += bflo(v1); ay += bfhi(v1);
            }
            for (; base < deg; base += 8) {          // predicated tail
                const int q = base + e8;
                const int act = (q < deg);
                const int cc = col[rs + (act ? q : 0)];
                unsigned v = yb[(size_t)cc * 8 + f8];
                if (!act) v = 0u;
                ax += bflo(v); ay += bfhi(v);
            }
            // combine slot groups (fixed order: ^8, ^16, ^32)
            ax += __shfl_xor(ax, 8);  ay += __shfl_xor(ay, 8);
            ax += __shfl_xor(ax, 16); ay += __shfl_xor(ay, 16);
            ax += __shfl_xor(ax, 32); ay += __shfl_xor(ay, 32);
            if (e8 == 0) {
                const int row = wv * 16 + i;
                *reinterpret_cast<float2*>(&tl[row * STR + c * 16 + 2 * f8]) =
                    make_float2(fmaxf(ax + bv.x, 0.f), fmaxf(ay + bv.y, 0.f));
            }
        }
    }
    __syncthreads();

    // ---- Phase B: u = relu(t @ w2 + b2) ----
    const int j0 = wv << 4;
    const int node = tile * 64 + lane;
    float a[16];
#pragma unroll
    for (int jj = 0; jj < 16; jj++) a[jj] = b2[j0 + jj];
    for (int k = 0; k < 64; k += 8) {
        float2 t0 = *reinterpret_cast<const float2*>(&tl[lane * STR + k]);
        float2 t1 = *reinterpret_cast<const float2*>(&tl[lane * STR + k + 2]);
        float2 t2 = *reinterpret_cast<const float2*>(&tl[lane * STR + k + 4]);
        float2 t3 = *reinterpret_cast<const float2*>(&tl[lane * STR + k + 6]);
        const float tv[8] = {t0.x, t0.y, t1.x, t1.y, t2.x, t2.y, t3.x, t3.y};
#pragma unroll
        for (int kk = 0; kk < 8; kk++)
#pragma unroll
            for (int jj = 0; jj < 16; jj++)
                a[jj] = fmaf(tv[kk], w2[(k + kk) * 64 + j0 + jj], a[jj]);
    }
#pragma unroll
    for (int jj = 0; jj < 16; jj++) a[jj] = fmaxf(a[jj], 0.f);

    if (LAST) {
        if (node < n) {
            float* orow = hout + (size_t)node * 64 + j0;
#pragma unroll
            for (int jj = 0; jj < 16; jj += 4) {
                *reinterpret_cast<float4*>(orow + jj) =
                    make_float4(a[jj], a[jj + 1], a[jj + 2], a[jj + 3]);
            }
        }
    } else {
        __syncthreads();
#pragma unroll
        for (int jj = 0; jj < 16; jj++) tl[lane * STR + j0 + jj] = a[jj];
        __syncthreads();
        float a2[16];
#pragma unroll
        for (int jj = 0; jj < 16; jj++) a2[jj] = 0.f;
        for (int k = 0; k < 64; k += 8) {
            float2 t0 = *reinterpret_cast<const float2*>(&tl[lane * STR + k]);
            float2 t1 = *reinterpret_cast<const float2*>(&tl[lane * STR + k + 2]);
            float2 t2 = *reinterpret_cast<const float2*>(&tl[lane * STR + k + 4]);
            float2 t3 = *reinterpret_cast<const float2*>(&tl[lane * STR + k + 6]);
            const float tv[8] = {t0.x, t0.y, t1.x, t1.y, t2.x, t2.y, t3.x, t3.y};
#pragma unroll
            for (int kk = 0; kk < 8; kk++)
#pragma unroll
                for (int jj = 0; jj < 16; jj++)
                    a2[jj] = fmaf(tv[kk], w1n[(k + kk) * 64 + j0 + jj], a2[jj]);
        }
        if (node < n) {
            unsigned pk[8];
#pragma unroll
            for (int jj = 0; jj < 8; jj++)
                pk[jj] = (unsigned)f2bf(a2[2 * jj]) | ((unsigned)f2bf(a2[2 * jj + 1]) << 16);
            // wave wv computed exactly strip wv -> strip-major store
            unsigned* yo = reinterpret_cast<unsigned*>(yout) + (size_t)wv * n8 + (size_t)node * 8;
            uint4* o = reinterpret_cast<uint4*>(yo);
            o[0] = make_uint4(pk[0], pk[1], pk[2], pk[3]);
            o[1] = make_uint4(pk[4], pk[5], pk[6], pk[7]);
        }
    }
}

// ---------------------------------------------------------------------------
// Pool stage 1: G*PARTS blocks; block (g,part) reduces a sub-range of graph g.
// ---------------------------------------------------------------------------
#define POOL_PARTS 16
__global__ __launch_bounds__(256) void pool_partial_kernel(
    const float* __restrict__ h, const int* __restrict__ batch,
    float* __restrict__ partials, int n) {
    const int g = blockIdx.x >> 4;
    const int part = blockIdx.x & 15;
    const int tid = threadIdx.x;
    auto lb = [&](int key) {
        int lo = 0, hi = n;
        while (lo < hi) {
            int mid = (lo + hi) >> 1;
            if (batch[mid] < key) lo = mid + 1;
            else hi = mid;
        }
        return lo;
    };
    const int lo = lb(g), hi = lb(g + 1);
    const int cnt = hi - lo;
    const int s0 = lo + (int)(((long long)cnt * part) / POOL_PARTS);
    const int s1 = lo + (int)(((long long)cnt * (part + 1)) / POOL_PARTS);

    const int f = tid & 63;
    const int qq = tid >> 6;
    float s = 0.f;
    for (int i = s0 + qq; i < s1; i += 4) s += h[(size_t)i * 64 + f];

    __shared__ float red[256];
    red[tid] = s;
    __syncthreads();
    if (tid < 64) {
        partials[(size_t)blockIdx.x * 64 + tid] =
            red[tid] + red[tid + 64] + red[tid + 128] + red[tid + 192];
    }
}

// ---------------------------------------------------------------------------
// Pool stage 2 + head MLP. One block per graph; reads 16 partials.
// ---------------------------------------------------------------------------
__global__ __launch_bounds__(64) void pool_head_kernel(
    const float* __restrict__ partials, const int* __restrict__ batch,
    const float* __restrict__ l1w, const float* __restrict__ l1b,
    const float* __restrict__ l2w, const float* __restrict__ l2b,
    float* __restrict__ out, int n) {
    const int g = blockIdx.x;
    const int tid = threadIdx.x;
    auto lb = [&](int key) {
        int lo = 0, hi = n;
        while (lo < hi) {
            int mid = (lo + hi) >> 1;
            if (batch[mid] < key) lo = mid + 1;
            else hi = mid;
        }
        return lo;
    };
    const int cnt = lb(g + 1) - lb(g);

    __shared__ float pooled[64];
    __shared__ float r[64];
    float v = 0.f;
#pragma unroll
    for (int p = 0; p < POOL_PARTS; p++)
        v += partials[(size_t)(g * POOL_PARTS + p) * 64 + tid];
    pooled[tid] = v / (float)((cnt > 1) ? cnt : 1);
    __syncthreads();
    float a = l1b[tid];
    for (int k = 0; k < 64; k++) a = fmaf(pooled[k], l1w[k * 64 + tid], a);
    r[tid] = fmaxf(a, 0.f);
    __syncthreads();
    if (tid < 2) {
        float a2 = l2b[tid];
        for (int k = 0; k < 64; k++) a2 = fmaf(r[k], l2w[k * 2 + tid], a2);
        out[g * 2 + tid] = a2;
    }
}

// ---------------------------------------------------------------------------

extern "C" void kernel_launch(void* const* d_in, const int* in_sizes, int n_in,
                              void* d_out, int out_size, void* d_ws, size_t ws_size,
                              hipStream_t stream) {
    const float* x    = (const float*)d_in[0];
    const int* ei     = (const int*)d_in[1];
    const int* batch  = (const int*)d_in[2];
    const float* l0w1 = (const float*)d_in[3];
    const float* l0b1 = (const float*)d_in[4];
    const float* l0w2 = (const float*)d_in[5];
    const float* l0b2 = (const float*)d_in[6];
    const float* l1w1 = (const float*)d_in[7];
    const float* l1b1 = (const float*)d_in[8];
    const float* l1w2 = (const float*)d_in[9];
    const float* l1b2 = (const float*)d_in[10];
    const float* l2w1 = (const float*)d_in[11];
    const float* l2b1 = (const float*)d_in[12];
    const float* l2w2 = (const float*)d_in[13];
    const float* l2b2 = (const float*)d_in[14];
    const float* lin1w = (const float*)d_in[15];
    const float* lin1b = (const float*)d_in[16];
    const float* lin2w = (const float*)d_in[17];
    const float* lin2b = (const float*)d_in[18];
    float* out = (float*)d_out;

    const int N  = in_sizes[2];
    const int E_ = in_sizes[1] / 2;
    const int K  = (N + 511) >> 9;
    const int G  = out_size / 2;

    char* ws = (char*)d_ws;
    size_t off = 0;
    auto alloc = [&](size_t bytes) {
        void* p = ws + off;
        off += (bytes + 255) & ~(size_t)255;
        return p;
    };
    int* rowptr  = (int*)alloc((size_t)(N + 1) * 4);
    int* col     = (int*)alloc((size_t)E_ * 4);
    int* gcount  = (int*)alloc(1024 * 4);
    int* bbase   = (int*)alloc(1025 * 4);
    int* gcursor = (int*)alloc(1024 * 4);
    float* partials = (float*)alloc((size_t)G * POOL_PARTS * 64 * 4);
    unsigned short* yA = (unsigned short*)alloc((size_t)N * 64 * 2);
    unsigned short* yB = (unsigned short*)alloc((size_t)N * 64 * 2);
    float* hbuf  = (float*)alloc((size_t)N * 64 * 4);
    unsigned* bpack = (unsigned*)hbuf;  // alias: bpack dead before fused2 writes hbuf
    (void)ws_size;

    const int nch = (E_ + 2047) / 2048;

    // --- CSR build (bucketed counting sort) ---
    zero1024_kernel<<<1, 1024, 0, stream>>>(gcount);
    count_buckets_kernel<<<nch, 256, 0, stream>>>(ei, gcount, E_);
    scan_buckets_kernel<<<1, 1024, 0, stream>>>(gcount, bbase, gcursor, rowptr, K, E_, N);
    bucketize_kernel<<<nch, 256, 0, stream>>>(ei, gcursor, bpack, E_);
    build_csr_kernel<<<K, 256, 0, stream>>>(bpack, bbase, rowptr, col, N);

    const int ntiles = (N + 63) / 64;

    // layer 0 proj, then 3 fused layers
    proj128_kernel<<<ntiles, 256, 0, stream>>>(x, yA, l0w1, N);
    fused_layer_kernel<false><<<ntiles, 256, 0, stream>>>(
        yA, rowptr, col, l0b1, l0w2, l0b2, l1w1, yB, nullptr, N);
    fused_layer_kernel<false><<<ntiles, 256, 0, stream>>>(
        yB, rowptr, col, l1b1, l1w2, l1b2, l2w1, yA, nullptr, N);
    fused_layer_kernel<true><<<ntiles, 256, 0, stream>>>(
        yA, rowptr, col, l2b1, l2w2, l2b2, nullptr, nullptr, hbuf, N);

    // --- pool + head ---
    pool_partial_kernel<<<G * POOL_PARTS, 256, 0, stream>>>(hbuf, batch, partials, N);
    pool_head_kernel<<<G, 64, 0, stream>>>(partials, batch, lin1w, lin1b, lin2w, lin2b, out, N);
}

// Round 10
// 295.490 us; speedup vs baseline: 2.2958x; 2.2958x over previous
//
#include <hip/hip_runtime.h>
#include <hip/hip_bf16.h>

// ---------------------------------------------------------------------------
// GIN model, proj-first formulation, fused per-layer kernel:
//   proj:  y0 = x @ w1_0                          (bf16 y, interleaved [n][64])
//   fused: t = relu(y_self + sum_nbr y + b1)      (LDS only, fp32)
//          u = relu(t @ w2 + b2)
//          y' = u @ w1_next  (bf16)   |  h = u (fp32, last layer)
// Gather: independent 16-lane quarters, one full 128B row per quarter via
//         uint2; 2-node software pipeline -> 8 row loads in flight per lane.
// CSR built per call via bucketed counting sort. Pool: 2-stage + head MLP.
// ---------------------------------------------------------------------------

__device__ inline unsigned short f2bf(float f) {
    union { __hip_bfloat16 b; unsigned short u; } cv;
    cv.b = __float2bfloat16(f);
    return cv.u;
}
__device__ inline float bflo(unsigned int v) {
    union { unsigned int u; float f; } c; c.u = v << 16; return c.f;
}
__device__ inline float bfhi(unsigned int v) {
    union { unsigned int u; float f; } c; c.u = v & 0xffff0000u; return c.f;
}

__global__ __launch_bounds__(1024) void zero1024_kernel(int* __restrict__ p) {
    p[threadIdx.x] = 0;
}

__global__ __launch_bounds__(256) void count_buckets_kernel(
    const int* __restrict__ ei, int* __restrict__ gcount, int E_) {
    __shared__ int hist[1024];
    const int tid = threadIdx.x;
    for (int i = tid; i < 1024; i += 256) hist[i] = 0;
    __syncthreads();
    const int base = blockIdx.x * 2048;
#pragma unroll
    for (int i = 0; i < 8; i++) {
        int e = base + i * 256 + tid;
        if (e < E_) atomicAdd(&hist[ei[E_ + e] >> 9], 1);
    }
    __syncthreads();
    for (int i = tid; i < 1024; i += 256)
        if (hist[i]) atomicAdd(&gcount[i], hist[i]);
}

__global__ __launch_bounds__(1024) void scan_buckets_kernel(
    const int* __restrict__ gcount, int* __restrict__ bbase,
    int* __restrict__ gcursor, int* __restrict__ rowptr, int K, int E_, int n) {
    __shared__ int sd[1024];
    const int tid = threadIdx.x;
    int v = (tid < K) ? gcount[tid] : 0;
    sd[tid] = v;
    __syncthreads();
    for (int off = 1; off < 1024; off <<= 1) {
        int x = (tid >= off) ? sd[tid - off] : 0;
        __syncthreads();
        sd[tid] += x;
        __syncthreads();
    }
    if (tid < K) {
        int excl = sd[tid] - v;
        bbase[tid] = excl;
        gcursor[tid] = excl;
    }
    if (tid == 0) {
        bbase[K] = E_;
        rowptr[n] = E_;
    }
}

__global__ __launch_bounds__(256) void bucketize_kernel(
    const int* __restrict__ ei, int* __restrict__ gcursor,
    unsigned* __restrict__ bpack, int E_) {
    __shared__ int hist[1024];
    __shared__ int gbase[1024];
    const int tid = threadIdx.x;
    for (int i = tid; i < 1024; i += 256) hist[i] = 0;
    __syncthreads();
    const int base = blockIdx.x * 2048;
    int bkt[8], rnk[8];
    unsigned pk[8];
#pragma unroll
    for (int i = 0; i < 8; i++) {
        int e = base + i * 256 + tid;
        bkt[i] = -1;
        if (e < E_) {
            int s = ei[e];
            int d = ei[E_ + e];
            bkt[i] = d >> 9;
            pk[i] = (unsigned)s | ((unsigned)(d & 511) << 22);
            rnk[i] = atomicAdd(&hist[bkt[i]], 1);
        }
    }
    __syncthreads();
    for (int i = tid; i < 1024; i += 256)
        if (hist[i]) gbase[i] = atomicAdd(&gcursor[i], hist[i]);
    __syncthreads();
#pragma unroll
    for (int i = 0; i < 8; i++)
        if (bkt[i] >= 0) bpack[gbase[bkt[i]] + rnk[i]] = pk[i];
}

__global__ __launch_bounds__(256) void build_csr_kernel(
    const unsigned* __restrict__ bpack, const int* __restrict__ bbase,
    int* __restrict__ rowptr, int* __restrict__ col, int n) {
    __shared__ int cnt[512];
    __shared__ int sp[256];
    const int tid = threadIdx.x;
    const int b = blockIdx.x;
    const int nstart = b << 9;
    const int estart = bbase[b];
    const int eend = bbase[b + 1];
    cnt[tid] = 0;
    cnt[tid + 256] = 0;
    __syncthreads();
    for (int e = estart + tid; e < eend; e += 256)
        atomicAdd(&cnt[bpack[e] >> 22], 1);
    __syncthreads();
    const int v0 = cnt[tid * 2], v1 = cnt[tid * 2 + 1];
    const int s = v0 + v1;
    sp[tid] = s;
    __syncthreads();
    for (int off = 1; off < 256; off <<= 1) {
        int x = (tid >= off) ? sp[tid - off] : 0;
        __syncthreads();
        sp[tid] += x;
        __syncthreads();
    }
    const int excl = sp[tid] - s;
    cnt[tid * 2] = excl;
    cnt[tid * 2 + 1] = excl + v0;
    const int node0 = nstart + tid * 2;
    if (node0 < n) rowptr[node0] = estart + excl;
    if (node0 + 1 < n) rowptr[node0 + 1] = estart + excl + v0;
    __syncthreads();
    for (int e = estart + tid; e < eend; e += 256) {
        unsigned p = bpack[e];
        int pos = estart + atomicAdd(&cnt[p >> 22], 1);
        col[pos] = (int)(p & 0x3FFFFFu);
    }
}

// ---------------------------------------------------------------------------
// proj128: y[n,64](bf16) = x[n,128] @ w[128,64]; x staged bf16x2 in LDS.
// ---------------------------------------------------------------------------
__global__ __launch_bounds__(256) void proj128_kernel(
    const float* __restrict__ x, unsigned short* __restrict__ y,
    const float* __restrict__ w, int n) {
    constexpr int STR = 66;              // u32 stride (2-way bank alias: free)
    __shared__ unsigned int xs[64 * STR];
    const int tid = threadIdx.x;
    const int tile = blockIdx.x;
    for (int idx = tid; idx < 64 * 64; idx += 256) {
        int r = idx >> 6;
        int c = idx & 63;
        int node = tile * 64 + r;
        float2 v = make_float2(0.f, 0.f);
        if (node < n) v = *reinterpret_cast<const float2*>(x + (size_t)node * 128 + c * 2);
        xs[r * STR + c] = (unsigned)f2bf(v.x) | ((unsigned)f2bf(v.y) << 16);
    }
    __syncthreads();
    const int lane = tid & 63;
    const int j0 = __builtin_amdgcn_readfirstlane(tid >> 6) << 4;
    float a[16];
#pragma unroll
    for (int jj = 0; jj < 16; jj++) a[jj] = 0.f;
    for (int k = 0; k < 128; k += 8) {
        unsigned p0 = xs[lane * STR + k / 2 + 0];
        unsigned p1 = xs[lane * STR + k / 2 + 1];
        unsigned p2 = xs[lane * STR + k / 2 + 2];
        unsigned p3 = xs[lane * STR + k / 2 + 3];
        const float tv[8] = {bflo(p0), bfhi(p0), bflo(p1), bfhi(p1),
                             bflo(p2), bfhi(p2), bflo(p3), bfhi(p3)};
#pragma unroll
        for (int kk = 0; kk < 8; kk++)
#pragma unroll
            for (int jj = 0; jj < 16; jj++)
                a[jj] = fmaf(tv[kk], w[(k + kk) * 64 + j0 + jj], a[jj]);
    }
    const int node = tile * 64 + lane;
    if (node < n) {
        unsigned pk[8];
#pragma unroll
        for (int jj = 0; jj < 8; jj++)
            pk[jj] = (unsigned)f2bf(a[2 * jj]) | ((unsigned)f2bf(a[2 * jj + 1]) << 16);
        uint4* orow = reinterpret_cast<uint4*>(y + (size_t)node * 64 + j0);
        orow[0] = make_uint4(pk[0], pk[1], pk[2], pk[3]);
        orow[1] = make_uint4(pk[4], pk[5], pk[6], pk[7]);
    }
}

// ---------------------------------------------------------------------------
// fused_layer: per 64-node tile
//   A: gather: quarter q (16 lanes, lane fl covers features 4*fl..4*fl+3 via
//      uint2) independently owns nodes [wv*16+4q, +4), pipelined in pairs:
//      8 row loads in flight per lane, no cross-lane reduction.
//   B: u = relu(t @ w2 + b2)
//   C/D (mid): y' = u @ w1n (bf16)   |  (last): h = u (fp32)
// ---------------------------------------------------------------------------
template <bool LAST>
__global__ __launch_bounds__(256) void fused_layer_kernel(
    const unsigned short* __restrict__ yin,
    const int* __restrict__ rowptr, const int* __restrict__ col,
    const float* __restrict__ b1,
    const float* __restrict__ w2, const float* __restrict__ b2,
    const float* __restrict__ w1n,
    unsigned short* __restrict__ yout, float* __restrict__ hout, int n) {
    constexpr int STR = 66;
    __shared__ float tl[64 * STR];
    const int tid = threadIdx.x;
    const int tile = blockIdx.x;
    const int lane = tid & 63;
    const int wv = __builtin_amdgcn_readfirstlane(tid >> 6);
    const int q = lane >> 4;
    const int fl = lane & 15;
    const uint2* y64 = reinterpret_cast<const uint2*>(yin);
    const float4 b1v = *reinterpret_cast<const float4*>(b1 + 4 * fl);

    // ---- Phase A: independent-quarter gather, 2-node pipeline ----
    const int rbase = wv * 16 + 4 * q;          // local row base for this quarter
#pragma unroll
    for (int j = 0; j < 2; ++j) {
        const int na = tile * 64 + rbase + 2 * j;
        const int nb = na + 1;
        const bool vA = (na < n), vB = (nb < n);
        int rsa = 0, dega = 0, rsb = 0, degb = 0;
        if (vA) { rsa = rowptr[na]; dega = rowptr[na + 1] - rsa; }
        if (vB) { rsb = rowptr[nb]; degb = rowptr[nb + 1] - rsb; }
        float ax, ay, az, aw, bx, by, bz, bw;
        {
            uint2 sa = make_uint2(0u, 0u), sb = make_uint2(0u, 0u);
            if (vA) sa = y64[(size_t)na * 16 + fl];
            if (vB) sb = y64[(size_t)nb * 16 + fl];
            ax = bflo(sa.x); ay = bfhi(sa.x); az = bflo(sa.y); aw = bfhi(sa.y);
            bx = bflo(sb.x); by = bfhi(sb.x); bz = bflo(sb.y); bw = bfhi(sb.y);
        }
        int pa = 0, pb = 0;
        while (pa + 4 <= dega && pb + 4 <= degb) {   // joint: 8 loads in flight
            const int ca0 = col[rsa + pa],     ca1 = col[rsa + pa + 1];
            const int ca2 = col[rsa + pa + 2], ca3 = col[rsa + pa + 3];
            const int cb0 = col[rsb + pb],     cb1 = col[rsb + pb + 1];
            const int cb2 = col[rsb + pb + 2], cb3 = col[rsb + pb + 3];
            const uint2 va0 = y64[(size_t)ca0 * 16 + fl];
            const uint2 va1 = y64[(size_t)ca1 * 16 + fl];
            const uint2 va2 = y64[(size_t)ca2 * 16 + fl];
            const uint2 va3 = y64[(size_t)ca3 * 16 + fl];
            const uint2 vb0 = y64[(size_t)cb0 * 16 + fl];
            const uint2 vb1 = y64[(size_t)cb1 * 16 + fl];
            const uint2 vb2 = y64[(size_t)cb2 * 16 + fl];
            const uint2 vb3 = y64[(size_t)cb3 * 16 + fl];
            ax += bflo(va0.x); ay += bfhi(va0.x); az += bflo(va0.y); aw += bfhi(va0.y);
            ax += bflo(va1.x); ay += bfhi(va1.x); az += bflo(va1.y); aw += bfhi(va1.y);
            ax += bflo(va2.x); ay += bfhi(va2.x); az += bflo(va2.y); aw += bfhi(va2.y);
            ax += bflo(va3.x); ay += bfhi(va3.x); az += bflo(va3.y); aw += bfhi(va3.y);
            bx += bflo(vb0.x); by += bfhi(vb0.x); bz += bflo(vb0.y); bw += bfhi(vb0.y);
            bx += bflo(vb1.x); by += bfhi(vb1.x); bz += bflo(vb1.y); bw += bfhi(vb1.y);
            bx += bflo(vb2.x); by += bfhi(vb2.x); bz += bflo(vb2.y); bw += bfhi(vb2.y);
            bx += bflo(vb3.x); by += bfhi(vb3.x); bz += bflo(vb3.y); bw += bfhi(vb3.y);
            pa += 4; pb += 4;
        }
        while (pa + 4 <= dega) {                     // drain A
            const int c0 = col[rsa + pa],     c1 = col[rsa + pa + 1];
            const int c2 = col[rsa + pa + 2], c3 = col[rsa + pa + 3];
            const uint2 v0 = y64[(size_t)c0 * 16 + fl];
            const uint2 v1 = y64[(size_t)c1 * 16 + fl];
            const uint2 v2 = y64[(size_t)c2 * 16 + fl];
            const uint2 v3 = y64[(size_t)c3 * 16 + fl];
            ax += bflo(v0.x); ay += bfhi(v0.x); az += bflo(v0.y); aw += bfhi(v0.y);
            ax += bflo(v1.x); ay += bfhi(v1.x); az += bflo(v1.y); aw += bfhi(v1.y);
            ax += bflo(v2.x); ay += bfhi(v2.x); az += bflo(v2.y); aw += bfhi(v2.y);
            ax += bflo(v3.x); ay += bfhi(v3.x); az += bflo(v3.y); aw += bfhi(v3.y);
            pa += 4;
        }
        while (pb + 4 <= degb) {                     // drain B
            const int c0 = col[rsb + pb],     c1 = col[rsb + pb + 1];
            const int c2 = col[rsb + pb + 2], c3 = col[rsb + pb + 3];
            const uint2 v0 = y64[(size_t)c0 * 16 + fl];
            const uint2 v1 = y64[(size_t)c1 * 16 + fl];
            const uint2 v2 = y64[(size_t)c2 * 16 + fl];
            const uint2 v3 = y64[(size_t)c3 * 16 + fl];
            bx += bflo(v0.x); by += bfhi(v0.x); bz += bflo(v0.y); bw += bfhi(v0.y);
            bx += bflo(v1.x); by += bfhi(v1.x); bz += bflo(v1.y); bw += bfhi(v1.y);
            bx += bflo(v2.x); by += bfhi(v2.x); bz += bflo(v2.y); bw += bfhi(v2.y);
            bx += bflo(v3.x); by += bfhi(v3.x); bz += bflo(v3.y); bw += bfhi(v3.y);
            pb += 4;
        }
        if (pa < dega) {                             // predicated tail A (<=3)
#pragma unroll
            for (int k = 0; k < 3; ++k) {
                const int idx = pa + k;
                const bool act = idx < dega;
                const int c = col[rsa + (act ? idx : 0)];
                uint2 v = y64[(size_t)c * 16 + fl];
                if (!act) { v.x = 0u; v.y = 0u; }
                ax += bflo(v.x); ay += bfhi(v.x); az += bflo(v.y); aw += bfhi(v.y);
            }
        }
        if (pb < degb) {                             // predicated tail B (<=3)
#pragma unroll
            for (int k = 0; k < 3; ++k) {
                const int idx = pb + k;
                const bool act = idx < degb;
                const int c = col[rsb + (act ? idx : 0)];
                uint2 v = y64[(size_t)c * 16 + fl];
                if (!act) { v.x = 0u; v.y = 0u; }
                bx += bflo(v.x); by += bfhi(v.x); bz += bflo(v.y); bw += bfhi(v.y);
            }
        }
        const int rowa = rbase + 2 * j;
        if (vA) {
            *reinterpret_cast<float2*>(&tl[rowa * STR + 4 * fl]) =
                make_float2(fmaxf(ax + b1v.x, 0.f), fmaxf(ay + b1v.y, 0.f));
            *reinterpret_cast<float2*>(&tl[rowa * STR + 4 * fl + 2]) =
                make_float2(fmaxf(az + b1v.z, 0.f), fmaxf(aw + b1v.w, 0.f));
        }
        if (vB) {
            *reinterpret_cast<float2*>(&tl[(rowa + 1) * STR + 4 * fl]) =
                make_float2(fmaxf(bx + b1v.x, 0.f), fmaxf(by + b1v.y, 0.f));
            *reinterpret_cast<float2*>(&tl[(rowa + 1) * STR + 4 * fl + 2]) =
                make_float2(fmaxf(bz + b1v.z, 0.f), fmaxf(bw + b1v.w, 0.f));
        }
    }
    __syncthreads();

    // ---- Phase B: u = relu(t @ w2 + b2) ----
    const int j0 = wv << 4;
    const int node = tile * 64 + lane;
    float a[16];
#pragma unroll
    for (int jj = 0; jj < 16; jj++) a[jj] = b2[j0 + jj];
    for (int k = 0; k < 64; k += 8) {
        float2 t0 = *reinterpret_cast<const float2*>(&tl[lane * STR + k]);
        float2 t1 = *reinterpret_cast<const float2*>(&tl[lane * STR + k + 2]);
        float2 t2 = *reinterpret_cast<const float2*>(&tl[lane * STR + k + 4]);
        float2 t3 = *reinterpret_cast<const float2*>(&tl[lane * STR + k + 6]);
        const float tv[8] = {t0.x, t0.y, t1.x, t1.y, t2.x, t2.y, t3.x, t3.y};
#pragma unroll
        for (int kk = 0; kk < 8; kk++)
#pragma unroll
            for (int jj = 0; jj < 16; jj++)
                a[jj] = fmaf(tv[kk], w2[(k + kk) * 64 + j0 + jj], a[jj]);
    }
#pragma unroll
    for (int jj = 0; jj < 16; jj++) a[jj] = fmaxf(a[jj], 0.f);

    if (LAST) {
        if (node < n) {
            float* orow = hout + (size_t)node * 64 + j0;
#pragma unroll
            for (int jj = 0; jj < 16; jj += 4) {
                *reinterpret_cast<float4*>(orow + jj) =
                    make_float4(a[jj], a[jj + 1], a[jj + 2], a[jj + 3]);
            }
        }
    } else {
        __syncthreads();
#pragma unroll
        for (int jj = 0; jj < 16; jj++) tl[lane * STR + j0 + jj] = a[jj];
        __syncthreads();
        float a2[16];
#pragma unroll
        for (int jj = 0; jj < 16; jj++) a2[jj] = 0.f;
        for (int k = 0; k < 64; k += 8) {
            float2 t0 = *reinterpret_cast<const float2*>(&tl[lane * STR + k]);
            float2 t1 = *reinterpret_cast<const float2*>(&tl[lane * STR + k + 2]);
            float2 t2 = *reinterpret_cast<const float2*>(&tl[lane * STR + k + 4]);
            float2 t3 = *reinterpret_cast<const float2*>(&tl[lane * STR + k + 6]);
            const float tv[8] = {t0.x, t0.y, t1.x, t1.y, t2.x, t2.y, t3.x, t3.y};
#pragma unroll
            for (int kk = 0; kk < 8; kk++)
#pragma unroll
                for (int jj = 0; jj < 16; jj++)
                    a2[jj] = fmaf(tv[kk], w1n[(k + kk) * 64 + j0 + jj], a2[jj]);
        }
        if (node < n) {
            unsigned pk[8];
#pragma unroll
            for (int jj = 0; jj < 8; jj++)
                pk[jj] = (unsigned)f2bf(a2[2 * jj]) | ((unsigned)f2bf(a2[2 * jj + 1]) << 16);
            uint4* orow = reinterpret_cast<uint4*>(yout + (size_t)node * 64 + j0);
            orow[0] = make_uint4(pk[0], pk[1], pk[2], pk[3]);
            orow[1] = make_uint4(pk[4], pk[5], pk[6], pk[7]);
        }
    }
}

// ---------------------------------------------------------------------------
// Pool stage 1: G*PARTS blocks; block (g,part) reduces a sub-range of graph g.
// ---------------------------------------------------------------------------
#define POOL_PARTS 16
__global__ __launch_bounds__(256) void pool_partial_kernel(
    const float* __restrict__ h, const int* __restrict__ batch,
    float* __restrict__ partials, int n) {
    const int g = blockIdx.x >> 4;
    const int part = blockIdx.x & 15;
    const int tid = threadIdx.x;
    auto lb = [&](int key) {
        int lo = 0, hi = n;
        while (lo < hi) {
            int mid = (lo + hi) >> 1;
            if (batch[mid] < key) lo = mid + 1;
            else hi = mid;
        }
        return lo;
    };
    const int lo = lb(g), hi = lb(g + 1);
    const int cnt = hi - lo;
    const int s0 = lo + (int)(((long long)cnt * part) / POOL_PARTS);
    const int s1 = lo + (int)(((long long)cnt * (part + 1)) / POOL_PARTS);

    const int f = tid & 63;
    const int qq = tid >> 6;
    float s = 0.f;
    for (int i = s0 + qq; i < s1; i += 4) s += h[(size_t)i * 64 + f];

    __shared__ float red[256];
    red[tid] = s;
    __syncthreads();
    if (tid < 64) {
        partials[(size_t)blockIdx.x * 64 + tid] =
            red[tid] + red[tid + 64] + red[tid + 128] + red[tid + 192];
    }
}

// ---------------------------------------------------------------------------
// Pool stage 2 + head MLP. One block per graph; reads 16 partials.
// ---------------------------------------------------------------------------
__global__ __launch_bounds__(64) void pool_head_kernel(
    const float* __restrict__ partials, const int* __restrict__ batch,
    const float* __restrict__ l1w, const float* __restrict__ l1b,
    const float* __restrict__ l2w, const float* __restrict__ l2b,
    float* __restrict__ out, int n) {
    const int g = blockIdx.x;
    const int tid = threadIdx.x;
    auto lb = [&](int key) {
        int lo = 0, hi = n;
        while (lo < hi) {
            int mid = (lo + hi) >> 1;
            if (batch[mid] < key) lo = mid + 1;
            else hi = mid;
        }
        return lo;
    };
    const int cnt = lb(g + 1) - lb(g);

    __shared__ float pooled[64];
    __shared__ float r[64];
    float v = 0.f;
#pragma unroll
    for (int p = 0; p < POOL_PARTS; p++)
        v += partials[(size_t)(g * POOL_PARTS + p) * 64 + tid];
    pooled[tid] = v / (float)((cnt > 1) ? cnt : 1);
    __syncthreads();
    float a = l1b[tid];
    for (int k = 0; k < 64; k++) a = fmaf(pooled[k], l1w[k * 64 + tid], a);
    r[tid] = fmaxf(a, 0.f);
    __syncthreads();
    if (tid < 2) {
        float a2 = l2b[tid];
        for (int k = 0; k < 64; k++) a2 = fmaf(r[k], l2w[k * 2 + tid], a2);
        out[g * 2 + tid] = a2;
    }
}

// ---------------------------------------------------------------------------

extern "C" void kernel_launch(void* const* d_in, const int* in_sizes, int n_in,
                              void* d_out, int out_size, void* d_ws, size_t ws_size,
                              hipStream_t stream) {
    const float* x    = (const float*)d_in[0];
    const int* ei     = (const int*)d_in[1];
    const int* batch  = (const int*)d_in[2];
    const float* l0w1 = (const float*)d_in[3];
    const float* l0b1 = (const float*)d_in[4];
    const float* l0w2 = (const float*)d_in[5];
    const float* l0b2 = (const float*)d_in[6];
    const float* l1w1 = (const float*)d_in[7];
    const float* l1b1 = (const float*)d_in[8];
    const float* l1w2 = (const float*)d_in[9];
    const float* l1b2 = (const float*)d_in[10];
    const float* l2w1 = (const float*)d_in[11];
    const float* l2b1 = (const float*)d_in[12];
    const float* l2w2 = (const float*)d_in[13];
    const float* l2b2 = (const float*)d_in[14];
    const float* lin1w = (const float*)d_in[15];
    const float* lin1b = (const float*)d_in[16];
    const float* lin2w = (const float*)d_in[17];
    const float* lin2b = (const float*)d_in[18];
    float* out = (float*)d_out;

    const int N  = in_sizes[2];
    const int E_ = in_sizes[1] / 2;
    const int K  = (N + 511) >> 9;
    const int G  = out_size / 2;

    char* ws = (char*)d_ws;
    size_t off = 0;
    auto alloc = [&](size_t bytes) {
        void* p = ws + off;
        off += (bytes + 255) & ~(size_t)255;
        return p;
    };
    int* rowptr  = (int*)alloc((size_t)(N + 1) * 4);
    int* col     = (int*)alloc((size_t)E_ * 4);
    int* gcount  = (int*)alloc(1024 * 4);
    int* bbase   = (int*)alloc(1025 * 4);
    int* gcursor = (int*)alloc(1024 * 4);
    float* partials = (float*)alloc((size_t)G * POOL_PARTS * 64 * 4);
    unsigned short* yA = (unsigned short*)alloc((size_t)N * 64 * 2);
    unsigned short* yB = (unsigned short*)alloc((size_t)N * 64 * 2);
    float* hbuf  = (float*)alloc((size_t)N * 64 * 4);
    unsigned* bpack = (unsigned*)hbuf;  // alias: bpack dead before fused2 writes hbuf
    (void)ws_size;

    const int nch = (E_ + 2047) / 2048;

    // --- CSR build (bucketed counting sort) ---
    zero1024_kernel<<<1, 1024, 0, stream>>>(gcount);
    count_buckets_kernel<<<nch, 256, 0, stream>>>(ei, gcount, E_);
    scan_buckets_kernel<<<1, 1024, 0, stream>>>(gcount, bbase, gcursor, rowptr, K, E_, N);
    bucketize_kernel<<<nch, 256, 0, stream>>>(ei, gcursor, bpack, E_);
    build_csr_kernel<<<K, 256, 0, stream>>>(bpack, bbase, rowptr, col, N);

    const int ntiles = (N + 63) / 64;

    // layer 0 proj, then 3 fused layers
    proj128_kernel<<<ntiles, 256, 0, stream>>>(x, yA, l0w1, N);
    fused_layer_kernel<false><<<ntiles, 256, 0, stream>>>(
        yA, rowptr, col, l0b1, l0w2, l0b2, l1w1, yB, nullptr, N);
    fused_layer_kernel<false><<<ntiles, 256, 0, stream>>>(
        yB, rowptr, col, l1b1, l1w2, l1b2, l2w1, yA, nullptr, N);
    fused_layer_kernel<true><<<ntiles, 256, 0, stream>>>(
        yA, rowptr, col, l2b1, l2w2, l2b2, nullptr, nullptr, hbuf, N);

    // --- pool + head ---
    pool_partial_kernel<<<G * POOL_PARTS, 256, 0, stream>>>(hbuf, batch, partials, N);
    pool_head_kernel<<<G, 64, 0, stream>>>(partials, batch, lin1w, lin1b, lin2w, lin2b, out, N);
}